// Round 1
// baseline (1383.827 us; speedup 1.0000x reference)
//
#include <hip/hip_runtime.h>
#include <math.h>

#define TSEQ 2048
#define NB   2
#define DM   1024
#define NH   16
#define DH   64
#define GN_EPS 1e-5f

// ---------------------------------------------------------------------------
// zero the GroupNorm stat accumulators (64 floats: 32 sums, 32 sumsqs)
// ---------------------------------------------------------------------------
__global__ __launch_bounds__(64) void zero_stats(float* __restrict__ stats) {
    stats[threadIdx.x] = 0.0f;
}

// ---------------------------------------------------------------------------
// QKV projection: O[m,n] = sum_k x[m,k] * W[n,k]   (y = x @ W.T)
// 64x64 tile, K-step 16, 256 threads, 4x4 micro-tile per thread. fp32.
// grid: (N/64=16, M/64=64, 3)  z: 0=Q 1=K 2=V
// ---------------------------------------------------------------------------
__global__ __launch_bounds__(256) void gemm_qkv(
    const float* __restrict__ x,
    const float* __restrict__ Wq, const float* __restrict__ Wk,
    const float* __restrict__ Wv,
    float* __restrict__ Q, float* __restrict__ K, float* __restrict__ V)
{
    const int z = blockIdx.z;
    const float* __restrict__ W = (z == 0) ? Wq : (z == 1) ? Wk : Wv;
    float* __restrict__ O       = (z == 0) ? Q  : (z == 1) ? K  : V;

    const int n0 = blockIdx.x * 64;
    const int m0 = blockIdx.y * 64;
    const int t  = threadIdx.x;
    const int tx = t & 15, ty = t >> 4;

    __shared__ float As[64][17];
    __shared__ float Bs[64][17];

    float acc[4][4] = {{0.f}};

    for (int k0 = 0; k0 < DM; k0 += 16) {
        const int kk = t & 15;
        const int r0 = t >> 4;   // 0..15
        #pragma unroll
        for (int p = 0; p < 4; ++p) {
            As[r0 + 16 * p][kk] = x[(size_t)(m0 + r0 + 16 * p) * DM + k0 + kk];
            Bs[r0 + 16 * p][kk] = W[(size_t)(n0 + r0 + 16 * p) * DM + k0 + kk];
        }
        __syncthreads();
        #pragma unroll
        for (int kkk = 0; kkk < 16; ++kkk) {
            float a[4], b[4];
            #pragma unroll
            for (int i = 0; i < 4; ++i) a[i] = As[ty * 4 + i][kkk];
            #pragma unroll
            for (int j = 0; j < 4; ++j) b[j] = Bs[tx * 4 + j][kkk];
            #pragma unroll
            for (int i = 0; i < 4; ++i)
                #pragma unroll
                for (int j = 0; j < 4; ++j)
                    acc[i][j] = fmaf(a[i], b[j], acc[i][j]);
        }
        __syncthreads();
    }

    #pragma unroll
    for (int i = 0; i < 4; ++i)
        #pragma unroll
        for (int j = 0; j < 4; ++j)
            O[(size_t)(m0 + ty * 4 + i) * DM + n0 + tx * 4 + j] = acc[i][j];
}

// ---------------------------------------------------------------------------
// Retention: per (b,h), Y = (Q K^T * decay / 8) @ V, causal decay
// gamma_h^(i-j).  One block per (b, h, 64-row tile).  Loops over causal
// 64-col tiles.  Also accumulates sum/sumsq of Y per (b,h) for GroupNorm.
// LDS: Qs + KSs (K tile, then reused for S tile) + Vs  = ~50 KB.
// grid: (T/64=32, H=16, B=2)
// ---------------------------------------------------------------------------
__global__ __launch_bounds__(256) void retention_kernel(
    const float* __restrict__ Q, const float* __restrict__ K,
    const float* __restrict__ V, float* __restrict__ Y,
    float* __restrict__ stats)
{
    const int i0 = blockIdx.x * 64;
    const int h  = blockIdx.y;
    const int b  = blockIdx.z;
    const int t  = threadIdx.x;
    const int tx = t & 15, ty = t >> 4;

    __shared__ float Qs[64][65];
    __shared__ float KSs[64][65];   // K tile, then aliased as S tile
    __shared__ float Vs[64][65];

    const size_t base = (size_t)b * TSEQ * DM + (size_t)h * DH;

    // load Q tile once
    #pragma unroll
    for (int p = 0; p < 16; ++p) {
        int idx = p * 256 + t;
        int r = idx >> 6, c = idx & 63;
        Qs[r][c] = Q[base + (size_t)(i0 + r) * DM + c];
    }

    const float gamma = 1.0f - exp2f(-5.0f - (float)h);
    const float l2g   = log2f(gamma);

    float acc[4][4] = {{0.f}};

    for (int j0 = 0; j0 <= i0; j0 += 64) {
        __syncthreads();   // prev-iter reads done (also guards Qs load, iter 0)
        #pragma unroll
        for (int p = 0; p < 16; ++p) {
            int idx = p * 256 + t;
            int r = idx >> 6, c = idx & 63;
            KSs[r][c] = K[base + (size_t)(j0 + r) * DM + c];
            Vs[r][c]  = V[base + (size_t)(j0 + r) * DM + c];
        }
        __syncthreads();

        // S = Q K^T  (4x4 per thread)
        float s[4][4] = {{0.f}};
        for (int d = 0; d < 64; ++d) {
            float a[4], bb[4];
            #pragma unroll
            for (int i = 0; i < 4; ++i) a[i] = Qs[ty * 4 + i][d];
            #pragma unroll
            for (int j = 0; j < 4; ++j) bb[j] = KSs[tx * 4 + j][d];
            #pragma unroll
            for (int i = 0; i < 4; ++i)
                #pragma unroll
                for (int j = 0; j < 4; ++j)
                    s[i][j] = fmaf(a[i], bb[j], s[i][j]);
        }
        __syncthreads();   // all K-tile reads done before aliasing as S

        // decay + scale, write S into KSs
        #pragma unroll
        for (int i = 0; i < 4; ++i)
            #pragma unroll
            for (int j = 0; j < 4; ++j) {
                int ti = i0 + ty * 4 + i;
                int tj = j0 + tx * 4 + j;
                int diff = ti - tj;
                float w = (diff >= 0) ? exp2f(l2g * (float)diff) * 0.125f : 0.0f;
                KSs[ty * 4 + i][tx * 4 + j] = s[i][j] * w;
            }
        __syncthreads();

        // Y += S @ V
        for (int c = 0; c < 64; ++c) {
            float a[4], bb[4];
            #pragma unroll
            for (int i = 0; i < 4; ++i) a[i] = KSs[ty * 4 + i][c];
            #pragma unroll
            for (int j = 0; j < 4; ++j) bb[j] = Vs[c][tx * 4 + j];
            #pragma unroll
            for (int i = 0; i < 4; ++i)
                #pragma unroll
                for (int j = 0; j < 4; ++j)
                    acc[i][j] = fmaf(a[i], bb[j], acc[i][j]);
        }
    }

    // write Y tile + local stats
    float lsum = 0.f, lsq = 0.f;
    #pragma unroll
    for (int i = 0; i < 4; ++i)
        #pragma unroll
        for (int j = 0; j < 4; ++j) {
            float v = acc[i][j];
            Y[base + (size_t)(i0 + ty * 4 + i) * DM + tx * 4 + j] = v;
            lsum += v;
            lsq  += v * v;
        }

    // block reduction (reuse Qs space; no aliasing with still-active reads)
    float* red0 = &Qs[0][0];
    float* red1 = red0 + 256;
    red0[t] = lsum;
    red1[t] = lsq;
    __syncthreads();
    for (int off = 128; off > 0; off >>= 1) {
        if (t < off) { red0[t] += red0[t + off]; red1[t] += red1[t + off]; }
        __syncthreads();
    }
    if (t == 0) {
        atomicAdd(&stats[b * NH + h],      red0[0]);
        atomicAdd(&stats[32 + b * NH + h], red1[0]);
    }
}

// ---------------------------------------------------------------------------
// GroupNorm finalize: per (b, channel) scale/shift
// yn = (y - mean)*rstd*w + bias  ->  y*scale + shift
// ---------------------------------------------------------------------------
__global__ __launch_bounds__(256) void gn_finalize(
    const float* __restrict__ stats,
    const float* __restrict__ gnw, const float* __restrict__ gnb,
    float* __restrict__ scale, float* __restrict__ shift)
{
    int idx = blockIdx.x * 256 + threadIdx.x;   // 0..2047
    if (idx >= NB * DM) return;
    int bb = idx >> 10;
    int c  = idx & (DM - 1);
    int hh = c >> 6;
    const float n = (float)(DH * TSEQ);         // 131072
    float mean = stats[bb * NH + hh] / n;
    float var  = stats[32 + bb * NH + hh] / n - mean * mean;
    float rstd = rsqrtf(var + GN_EPS);
    float sc = rstd * gnw[c];
    scale[idx] = sc;
    shift[idx] = gnb[c] - mean * sc;
}

// ---------------------------------------------------------------------------
// Output projection with fused GroupNorm apply on the A operand:
// out[m,n] = sum_k (Y[m,k]*scale[b,k]+shift[b,k]) * Wo[n,k]
// grid: (16, 64)
// ---------------------------------------------------------------------------
__global__ __launch_bounds__(256) void gemm_out(
    const float* __restrict__ Y, const float* __restrict__ Wo,
    const float* __restrict__ scale, const float* __restrict__ shift,
    float* __restrict__ out)
{
    const int n0 = blockIdx.x * 64;
    const int m0 = blockIdx.y * 64;
    const int t  = threadIdx.x;
    const int tx = t & 15, ty = t >> 4;

    __shared__ float As[64][17];
    __shared__ float Bs[64][17];

    float acc[4][4] = {{0.f}};

    for (int k0 = 0; k0 < DM; k0 += 16) {
        const int kk = t & 15;
        const int r0 = t >> 4;
        #pragma unroll
        for (int p = 0; p < 4; ++p) {
            int m = m0 + r0 + 16 * p;
            int b = m >> 11;                    // m / 2048
            int k = k0 + kk;
            float yv = Y[(size_t)m * DM + k];
            As[r0 + 16 * p][kk] = yv * scale[b * DM + k] + shift[b * DM + k];
            Bs[r0 + 16 * p][kk] = Wo[(size_t)(n0 + r0 + 16 * p) * DM + k];
        }
        __syncthreads();
        #pragma unroll
        for (int kkk = 0; kkk < 16; ++kkk) {
            float a[4], b[4];
            #pragma unroll
            for (int i = 0; i < 4; ++i) a[i] = As[ty * 4 + i][kkk];
            #pragma unroll
            for (int j = 0; j < 4; ++j) b[j] = Bs[tx * 4 + j][kkk];
            #pragma unroll
            for (int i = 0; i < 4; ++i)
                #pragma unroll
                for (int j = 0; j < 4; ++j)
                    acc[i][j] = fmaf(a[i], b[j], acc[i][j]);
        }
        __syncthreads();
    }

    #pragma unroll
    for (int i = 0; i < 4; ++i)
        #pragma unroll
        for (int j = 0; j < 4; ++j)
            out[(size_t)(m0 + ty * 4 + i) * DM + n0 + tx * 4 + j] = acc[i][j];
}

// ---------------------------------------------------------------------------
extern "C" void kernel_launch(void* const* d_in, const int* in_sizes, int n_in,
                              void* d_out, int out_size, void* d_ws, size_t ws_size,
                              hipStream_t stream)
{
    const float* x   = (const float*)d_in[0];
    const float* Wq  = (const float*)d_in[1];
    const float* Wk  = (const float*)d_in[2];
    const float* Wv  = (const float*)d_in[3];
    const float* Wo  = (const float*)d_in[4];
    const float* gnw = (const float*)d_in[5];
    const float* gnb = (const float*)d_in[6];
    float* out = (float*)d_out;

    const size_t MAT = (size_t)NB * TSEQ * DM;       // 4,194,304 floats
    const size_t need_floats = 4 * MAT + 64 + 2 * (size_t)NB * DM;
    if (ws_size < need_floats * sizeof(float)) return;   // workspace too small

    float* ws    = (float*)d_ws;
    float* Q     = ws;
    float* K     = ws + MAT;
    float* V     = ws + 2 * MAT;
    float* Y     = ws + 3 * MAT;
    float* stats = ws + 4 * MAT;          // 64 floats
    float* scale = stats + 64;            // NB*DM
    float* shift = scale + (size_t)NB * DM;

    zero_stats<<<1, 64, 0, stream>>>(stats);
    gemm_qkv<<<dim3(DM / 64, (NB * TSEQ) / 64, 3), 256, 0, stream>>>(
        x, Wq, Wk, Wv, Q, K, V);
    retention_kernel<<<dim3(TSEQ / 64, NH, NB), 256, 0, stream>>>(
        Q, K, V, Y, stats);
    gn_finalize<<<dim3((NB * DM + 255) / 256), 256, 0, stream>>>(
        stats, gnw, gnb, scale, shift);
    gemm_out<<<dim3(DM / 64, (NB * TSEQ) / 64), 256, 0, stream>>>(
        Y, Wo, scale, shift, out);
}

// Round 2
// 373.691 us; speedup vs baseline: 3.7031x; 3.7031x over previous
//
#include <hip/hip_runtime.h>
#include <math.h>

#define TSEQ 2048
#define NB   2
#define DM   1024
#define NH   16
#define DH   64
#define GN_EPS 1e-5f

typedef short v8s __attribute__((ext_vector_type(8)));
typedef short v4s __attribute__((ext_vector_type(4)));
typedef float v4f __attribute__((ext_vector_type(4)));

__device__ __forceinline__ short f2bf(float f) {
    union { float f; unsigned u; } c; c.f = f;
    unsigned u = c.u;
    unsigned r = (u + 0x7fffu + ((u >> 16) & 1u)) >> 16;   // RNE
    return (short)r;
}

// ---------------------------------------------------------------------------
// cast x and the 4 weight matrices to bf16; zero the GN stats
// ---------------------------------------------------------------------------
__global__ __launch_bounds__(256) void cast_kernel(
    const float* __restrict__ x,
    const float* __restrict__ Wq, const float* __restrict__ Wk,
    const float* __restrict__ Wv, const float* __restrict__ Wo,
    short* __restrict__ xbf, short* __restrict__ wbf, float* __restrict__ stats)
{
    if (blockIdx.x == 0 && threadIdx.x < 64) stats[threadIdx.x] = 0.0f;
    const int NX = NB * TSEQ * DM;            // 4,194,304
    const int NW = DM * DM;                   // 1,048,576
    const int total4 = (NX + 4 * NW) / 4;     // 2,097,152
    for (int i = blockIdx.x * 256 + threadIdx.x; i < total4;
         i += gridDim.x * 256) {
        int e = i * 4;
        const float* src; short* dst;
        if (e < NX) { src = x + e; dst = xbf + e; }
        else {
            int o = e - NX;
            int w = o >> 20;
            int r = o & (NW - 1);
            src = (w == 0 ? Wq : w == 1 ? Wk : w == 2 ? Wv : Wo) + r;
            dst = wbf + o;
        }
        v4f v = *(const v4f*)src;
        v4s s;
        #pragma unroll
        for (int j = 0; j < 4; ++j) s[j] = f2bf(v[j]);
        *(v4s*)dst = s;
    }
}

// ---------------------------------------------------------------------------
// QKV projection, bf16 MFMA, no LDS (A and B frags are contiguous 16B loads,
// L2-resident).  Block = 128x128, 4 waves in 2x2, each 64x64 (4x4 MFMA tiles).
// grid (DM/128=8, M/128=32, 3).  z=2 writes V transposed: Vt[b][h*64+d][t].
// ---------------------------------------------------------------------------
__global__ __launch_bounds__(256) void gemm_qkv_mfma(
    const short* __restrict__ xbf, const short* __restrict__ wbf,
    short* __restrict__ Qb, short* __restrict__ Kb, short* __restrict__ Vt)
{
    const int z = blockIdx.z;
    const short* __restrict__ B = wbf + (size_t)z * (DM * DM);
    const int n0 = blockIdx.x * 128, m0 = blockIdx.y * 128;
    const int t = threadIdx.x, l = t & 63, w = t >> 6;
    const int wr = (w >> 1) * 64, wc = (w & 1) * 64;
    const int lr = l & 15, lk = (l >> 4) * 8;

    const short* Ap = xbf + (size_t)(m0 + wr + lr) * DM + lk;
    const short* Bp = B   + (size_t)(n0 + wc + lr) * DM + lk;

    v4f acc[4][4];
    #pragma unroll
    for (int i = 0; i < 4; ++i)
        #pragma unroll
        for (int j = 0; j < 4; ++j) acc[i][j] = (v4f){0.f, 0.f, 0.f, 0.f};

    #pragma unroll 2
    for (int k0 = 0; k0 < DM; k0 += 32) {
        v8s a[4], bb[4];
        #pragma unroll
        for (int i = 0; i < 4; ++i) {
            a[i]  = *(const v8s*)(Ap + (size_t)i * 16 * DM + k0);
            bb[i] = *(const v8s*)(Bp + (size_t)i * 16 * DM + k0);
        }
        #pragma unroll
        for (int i = 0; i < 4; ++i)
            #pragma unroll
            for (int j = 0; j < 4; ++j)
                acc[i][j] = __builtin_amdgcn_mfma_f32_16x16x32_bf16(
                    a[i], bb[j], acc[i][j], 0, 0, 0);
    }

    if (z < 2) {
        short* __restrict__ O = (z == 0) ? Qb : Kb;
        #pragma unroll
        for (int i = 0; i < 4; ++i) {
            int row = m0 + wr + i * 16 + (l >> 4) * 4;
            #pragma unroll
            for (int j = 0; j < 4; ++j) {
                int col = n0 + wc + j * 16 + lr;
                #pragma unroll
                for (int r = 0; r < 4; ++r)
                    O[(size_t)(row + r) * DM + col] = f2bf(acc[i][j][r]);
            }
        }
    } else {
        #pragma unroll
        for (int i = 0; i < 4; ++i) {
            int row  = m0 + wr + i * 16 + (l >> 4) * 4;
            int bidx = row >> 11, tb = row & (TSEQ - 1);
            #pragma unroll
            for (int j = 0; j < 4; ++j) {
                int col = n0 + wc + j * 16 + lr;
                v4s pk;
                #pragma unroll
                for (int r = 0; r < 4; ++r) pk[r] = f2bf(acc[i][j][r]);
                *(v4s*)(Vt + ((size_t)bidx << 21) + ((size_t)col << 11) + tb) = pk;
            }
        }
    }
}

// ---------------------------------------------------------------------------
// Retention: Y = (Q K^T * gamma^(i-j) / 8) @ V, causal.  bf16 MFMA.
// Block = (b, h, 64-row i-tile), 4 waves each owning 16 rows.  S' goes
// through a wave-private XOR-swizzled LDS strip (16x64 bf16).
// grid (32, 16, 2).
// ---------------------------------------------------------------------------
__global__ __launch_bounds__(256) void retention_mfma(
    const short* __restrict__ Qb, const short* __restrict__ Kb,
    const short* __restrict__ Vt, float* __restrict__ Y,
    float* __restrict__ stats)
{
    const int i0 = blockIdx.x * 64;
    const int h  = blockIdx.y, b = blockIdx.z;
    const int t  = threadIdx.x, l = t & 63, w = t >> 6;
    const int lr = l & 15, g = l >> 4;      // g = 0..3

    __shared__ short S_lds[4][16 * 64];     // per-wave 16x64 bf16 strip
    short* Sw = S_lds[w];

    const float gamma = 1.0f - exp2f(-5.0f - (float)h);
    const float l2g   = log2f(gamma);

    // Q fragments (A-layout): row = i0 + w*16 + lr, k contiguous
    const size_t qoff = (size_t)(b * TSEQ + i0 + w * 16 + lr) * DM + h * DH;
    v8s qf0 = *(const v8s*)(Qb + qoff + g * 8);
    v8s qf1 = *(const v8s*)(Qb + qoff + 32 + g * 8);

    v4f y[4];
    #pragma unroll
    for (int d = 0; d < 4; ++d) y[d] = (v4f){0.f, 0.f, 0.f, 0.f};

    const size_t kbase  = (size_t)(b * TSEQ) * DM + h * DH;
    const size_t vtbase = ((size_t)b * 1024 + h * 64) * 2048;

    for (int j0 = 0; j0 <= i0; j0 += 64) {
        // ---- S = Q K^T (B-frag of K^T = contiguous K rows) ----
        v4f s[4];
        #pragma unroll
        for (int n = 0; n < 4; ++n) {
            const short* kp = Kb + kbase + (size_t)(j0 + n * 16 + lr) * DM;
            v8s k0v = *(const v8s*)(kp + g * 8);
            v8s k1v = *(const v8s*)(kp + 32 + g * 8);
            v4f a = (v4f){0.f, 0.f, 0.f, 0.f};
            a = __builtin_amdgcn_mfma_f32_16x16x32_bf16(qf0, k0v, a, 0, 0, 0);
            a = __builtin_amdgcn_mfma_f32_16x16x32_bf16(qf1, k1v, a, 0, 0, 0);
            s[n] = a;
        }

        // ---- decay + scale, convert to bf16, store to swizzled LDS ----
        const int  ibase = i0 - j0 + w * 16 + g * 4;   // i - j0 for reg r=0
        const bool diag  = (j0 == i0);
        float rowf[4];
        #pragma unroll
        for (int r = 0; r < 4; ++r)
            rowf[r] = exp2f(l2g * (float)(ibase + r)) * 0.125f;
        #pragma unroll
        for (int n = 0; n < 4; ++n) {
            int jl = n * 16 + lr;
            float cf = exp2f(-l2g * (float)jl);
            #pragma unroll
            for (int r = 0; r < 4; ++r) {
                float v = s[n][r] * rowf[r] * cf;
                if (diag && (ibase + r - jl) < 0) v = 0.0f;
                int row  = g * 4 + r;
                int byte = (row * 128 + jl * 2) ^ ((row & 7) << 4);
                *(short*)((char*)Sw + byte) = f2bf(v);
            }
        }
        __syncthreads();

        // ---- Y += S' @ V  (A-frag from swizzled LDS, B-frag from Vt) ----
        #pragma unroll
        for (int ks = 0; ks < 2; ++ks) {
            int byte = (lr * 128 + ks * 64 + g * 16) ^ ((lr & 7) << 4);
            v8s sa = *(const v8s*)((char*)Sw + byte);
            #pragma unroll
            for (int dt = 0; dt < 4; ++dt) {
                const short* vp = Vt + vtbase + (size_t)(dt * 16 + lr) * 2048
                                  + j0 + ks * 32 + g * 8;
                v8s vf = *(const v8s*)vp;
                y[dt] = __builtin_amdgcn_mfma_f32_16x16x32_bf16(sa, vf, y[dt],
                                                                0, 0, 0);
            }
        }
        __syncthreads();
    }

    // ---- write Y (fp32) + GN stats ----
    float lsum = 0.f, lsq = 0.f;
    #pragma unroll
    for (int dt = 0; dt < 4; ++dt) {
        #pragma unroll
        for (int r = 0; r < 4; ++r) {
            float v = y[dt][r];
            size_t row = (size_t)(b * TSEQ + i0 + w * 16 + g * 4 + r);
            Y[row * DM + h * DH + dt * 16 + lr] = v;
            lsum += v; lsq += v * v;
        }
    }
    #pragma unroll
    for (int m = 32; m; m >>= 1) {
        lsum += __shfl_xor(lsum, m, 64);
        lsq  += __shfl_xor(lsq,  m, 64);
    }
    if (l == 0) {
        atomicAdd(&stats[b * NH + h],      lsum);
        atomicAdd(&stats[32 + b * NH + h], lsq);
    }
}

// ---------------------------------------------------------------------------
// GroupNorm finalize: per (b, channel) scale/shift
// ---------------------------------------------------------------------------
__global__ __launch_bounds__(256) void gn_finalize(
    const float* __restrict__ stats,
    const float* __restrict__ gnw, const float* __restrict__ gnb,
    float* __restrict__ scale, float* __restrict__ shift)
{
    int idx = blockIdx.x * 256 + threadIdx.x;
    if (idx >= NB * DM) return;
    int bb = idx >> 10;
    int c  = idx & (DM - 1);
    int hh = c >> 6;
    const float n = (float)(DH * TSEQ);
    float mean = stats[bb * NH + hh] / n;
    float var  = stats[32 + bb * NH + hh] / n - mean * mean;
    float rstd = rsqrtf(var + GN_EPS);
    float sc = rstd * gnw[c];
    scale[idx] = sc;
    shift[idx] = gnb[c] - mean * sc;
}

// ---------------------------------------------------------------------------
// Apply GN -> bf16 (input to the output projection)
// ---------------------------------------------------------------------------
__global__ __launch_bounds__(256) void gn_apply(
    const float* __restrict__ Y, const float* __restrict__ scale,
    const float* __restrict__ shift, short* __restrict__ Ybf)
{
    const int total4 = (NB * TSEQ * DM) / 4;   // 1,048,576
    for (int i = blockIdx.x * 256 + threadIdx.x; i < total4;
         i += gridDim.x * 256) {
        int e = i * 4;
        int c = e & (DM - 1);
        int bb = e >> 21;
        v4f yv = *(const v4f*)(Y + e);
        v4f sc = *(const v4f*)(scale + bb * DM + c);
        v4f sh = *(const v4f*)(shift + bb * DM + c);
        v4s o;
        #pragma unroll
        for (int j = 0; j < 4; ++j) o[j] = f2bf(yv[j] * sc[j] + sh[j]);
        *(v4s*)(Ybf + e) = o;
    }
}

// ---------------------------------------------------------------------------
// Output projection: out = Ybf @ Wo^T, fp32 out.  Same structure as qkv GEMM.
// grid (8, 32)
// ---------------------------------------------------------------------------
__global__ __launch_bounds__(256) void gemm_out_mfma(
    const short* __restrict__ Ybf, const short* __restrict__ Wob,
    float* __restrict__ out)
{
    const int n0 = blockIdx.x * 128, m0 = blockIdx.y * 128;
    const int t = threadIdx.x, l = t & 63, w = t >> 6;
    const int wr = (w >> 1) * 64, wc = (w & 1) * 64;
    const int lr = l & 15, lk = (l >> 4) * 8;

    const short* Ap = Ybf + (size_t)(m0 + wr + lr) * DM + lk;
    const short* Bp = Wob + (size_t)(n0 + wc + lr) * DM + lk;

    v4f acc[4][4];
    #pragma unroll
    for (int i = 0; i < 4; ++i)
        #pragma unroll
        for (int j = 0; j < 4; ++j) acc[i][j] = (v4f){0.f, 0.f, 0.f, 0.f};

    #pragma unroll 2
    for (int k0 = 0; k0 < DM; k0 += 32) {
        v8s a[4], bb[4];
        #pragma unroll
        for (int i = 0; i < 4; ++i) {
            a[i]  = *(const v8s*)(Ap + (size_t)i * 16 * DM + k0);
            bb[i] = *(const v8s*)(Bp + (size_t)i * 16 * DM + k0);
        }
        #pragma unroll
        for (int i = 0; i < 4; ++i)
            #pragma unroll
            for (int j = 0; j < 4; ++j)
                acc[i][j] = __builtin_amdgcn_mfma_f32_16x16x32_bf16(
                    a[i], bb[j], acc[i][j], 0, 0, 0);
    }

    #pragma unroll
    for (int i = 0; i < 4; ++i) {
        int row = m0 + wr + i * 16 + (l >> 4) * 4;
        #pragma unroll
        for (int j = 0; j < 4; ++j) {
            int col = n0 + wc + j * 16 + lr;
            #pragma unroll
            for (int r = 0; r < 4; ++r)
                out[(size_t)(row + r) * DM + col] = acc[i][j][r];
        }
    }
}

// ---------------------------------------------------------------------------
extern "C" void kernel_launch(void* const* d_in, const int* in_sizes, int n_in,
                              void* d_out, int out_size, void* d_ws, size_t ws_size,
                              hipStream_t stream)
{
    const float* x   = (const float*)d_in[0];
    const float* Wq  = (const float*)d_in[1];
    const float* Wk  = (const float*)d_in[2];
    const float* Wv  = (const float*)d_in[3];
    const float* Wo  = (const float*)d_in[4];
    const float* gnw = (const float*)d_in[5];
    const float* gnb = (const float*)d_in[6];
    float* out = (float*)d_out;

    // workspace carve (bytes)
    char* wsb = (char*)d_ws;
    size_t o = 0;
    float* Y    = (float*)(wsb + o); o += (size_t)NB * TSEQ * DM * 4;   // 16,777,216
    short* Qb   = (short*)(wsb + o); o += (size_t)NB * TSEQ * DM * 2;   //  8,388,608
    short* Kb   = (short*)(wsb + o); o += (size_t)NB * TSEQ * DM * 2;
    short* Vt   = (short*)(wsb + o); o += (size_t)NB * TSEQ * DM * 2;
    short* xbf  = (short*)(wsb + o); o += (size_t)NB * TSEQ * DM * 2;
    short* wbf  = (short*)(wsb + o); o += (size_t)4 * DM * DM * 2;      //  8,388,608
    short* Ybf  = (short*)(wsb + o); o += (size_t)NB * TSEQ * DM * 2;
    float* stats = (float*)(wsb + o); o += 256;
    float* scale = (float*)(wsb + o); o += (size_t)NB * DM * 4;
    float* shift = (float*)(wsb + o); o += (size_t)NB * DM * 4;
    if (ws_size < o) return;

    cast_kernel<<<2048, 256, 0, stream>>>(x, Wq, Wk, Wv, Wo, xbf, wbf, stats);
    gemm_qkv_mfma<<<dim3(DM / 128, (NB * TSEQ) / 128, 3), 256, 0, stream>>>(
        xbf, wbf, Qb, Kb, Vt);
    retention_mfma<<<dim3(TSEQ / 64, NH, NB), 256, 0, stream>>>(
        Qb, Kb, Vt, Y, stats);
    gn_finalize<<<dim3((NB * DM + 255) / 256), 256, 0, stream>>>(
        stats, gnw, gnb, scale, shift);
    gn_apply<<<2048, 256, 0, stream>>>(Y, scale, shift, Ybf);
    gemm_out_mfma<<<dim3(DM / 128, (NB * TSEQ) / 128), 256, 0, stream>>>(
        Ybf, wbf + 3 * (size_t)DM * DM, out);
}

// Round 3
// 292.225 us; speedup vs baseline: 4.7355x; 1.2788x over previous
//
#include <hip/hip_runtime.h>
#include <math.h>

#define TSEQ 2048
#define NB   2
#define DM   1024
#define NH   16
#define DH   64
#define GN_EPS 1e-5f

typedef short v8s __attribute__((ext_vector_type(8)));
typedef short v4s __attribute__((ext_vector_type(4)));
typedef float v4f __attribute__((ext_vector_type(4)));

__device__ __forceinline__ short f2bf(float f) {
    union { float f; unsigned u; } c; c.f = f;
    unsigned u = c.u;
    unsigned r = (u + 0x7fffu + ((u >> 16) & 1u)) >> 16;   // RNE
    return (short)r;
}

// ---------------------------------------------------------------------------
// cast x and the 4 weight matrices to bf16; zero the GN stats
// ---------------------------------------------------------------------------
__global__ __launch_bounds__(256) void cast_kernel(
    const float* __restrict__ x,
    const float* __restrict__ Wq, const float* __restrict__ Wk,
    const float* __restrict__ Wv, const float* __restrict__ Wo,
    short* __restrict__ xbf, short* __restrict__ wbf, float* __restrict__ stats)
{
    if (blockIdx.x == 0 && threadIdx.x < 64) stats[threadIdx.x] = 0.0f;
    const int NX = NB * TSEQ * DM;            // 4,194,304
    const int NW = DM * DM;                   // 1,048,576
    const int total4 = (NX + 4 * NW) / 4;     // 2,097,152
    for (int i = blockIdx.x * 256 + threadIdx.x; i < total4;
         i += gridDim.x * 256) {
        int e = i * 4;
        const float* src; short* dst;
        if (e < NX) { src = x + e; dst = xbf + e; }
        else {
            int o = e - NX;
            int w = o >> 20;
            int r = o & (NW - 1);
            src = (w == 0 ? Wq : w == 1 ? Wk : w == 2 ? Wv : Wo) + r;
            dst = wbf + o;
        }
        v4f v = *(const v4f*)src;
        v4s s;
        #pragma unroll
        for (int j = 0; j < 4; ++j) s[j] = f2bf(v[j]);
        *(v4s*)dst = s;
    }
}

// ---------------------------------------------------------------------------
// QKV projection, bf16 MFMA, no LDS (A and B frags are contiguous 16B loads,
// L2-resident).  Block = 128x128, 4 waves in 2x2, each 64x64.
// grid (DM/128=8, M/128=32, 3).  z=2 writes V transposed: Vt[b][h*64+d][t].
// ---------------------------------------------------------------------------
__global__ __launch_bounds__(256) void gemm_qkv_mfma(
    const short* __restrict__ xbf, const short* __restrict__ wbf,
    short* __restrict__ Qb, short* __restrict__ Kb, short* __restrict__ Vt)
{
    const int z = blockIdx.z;
    const short* __restrict__ B = wbf + (size_t)z * (DM * DM);
    const int n0 = blockIdx.x * 128, m0 = blockIdx.y * 128;
    const int t = threadIdx.x, l = t & 63, w = t >> 6;
    const int wr = (w >> 1) * 64, wc = (w & 1) * 64;
    const int lr = l & 15, lk = (l >> 4) * 8;

    const short* Ap = xbf + (size_t)(m0 + wr + lr) * DM + lk;
    const short* Bp = B   + (size_t)(n0 + wc + lr) * DM + lk;

    v4f acc[4][4];
    #pragma unroll
    for (int i = 0; i < 4; ++i)
        #pragma unroll
        for (int j = 0; j < 4; ++j) acc[i][j] = (v4f){0.f, 0.f, 0.f, 0.f};

    #pragma unroll 2
    for (int k0 = 0; k0 < DM; k0 += 32) {
        v8s a[4], bb[4];
        #pragma unroll
        for (int i = 0; i < 4; ++i) {
            a[i]  = *(const v8s*)(Ap + (size_t)i * 16 * DM + k0);
            bb[i] = *(const v8s*)(Bp + (size_t)i * 16 * DM + k0);
        }
        #pragma unroll
        for (int i = 0; i < 4; ++i)
            #pragma unroll
            for (int j = 0; j < 4; ++j)
                acc[i][j] = __builtin_amdgcn_mfma_f32_16x16x32_bf16(
                    a[i], bb[j], acc[i][j], 0, 0, 0);
    }

    if (z < 2) {
        short* __restrict__ O = (z == 0) ? Qb : Kb;
        #pragma unroll
        for (int i = 0; i < 4; ++i) {
            int row = m0 + wr + i * 16 + (l >> 4) * 4;
            #pragma unroll
            for (int j = 0; j < 4; ++j) {
                int col = n0 + wc + j * 16 + lr;
                #pragma unroll
                for (int r = 0; r < 4; ++r)
                    O[(size_t)(row + r) * DM + col] = f2bf(acc[i][j][r]);
            }
        }
    } else {
        #pragma unroll
        for (int i = 0; i < 4; ++i) {
            int row  = m0 + wr + i * 16 + (l >> 4) * 4;
            int bidx = row >> 11, tb = row & (TSEQ - 1);
            #pragma unroll
            for (int j = 0; j < 4; ++j) {
                int col = n0 + wc + j * 16 + lr;
                v4s pk;
                #pragma unroll
                for (int r = 0; r < 4; ++r) pk[r] = f2bf(acc[i][j][r]);
                *(v4s*)(Vt + ((size_t)bidx << 21) + ((size_t)col << 11) + tb) = pk;
            }
        }
    }
}

// ---------------------------------------------------------------------------
// Retention: Y = (Q K^T * gamma^(i-j) / 8) @ V, causal.  bf16 MFMA.
// Block = (b, h): 8 waves, 512 threads.  Wave w (p=w>>2, q=w&3) processes
// rows [q*16, q*16+16) of i-tile A = blockIdx.x and i-tile B = 31-blockIdx.x,
// taking j-tiles of parity p descending from the diagonal -> every wave does
// the same ~16.5 iterations (perfect balance).  No barriers in the j-loop
// (per-wave LDS strips); parity partials combined via padded LDS per phase.
// grid (16, 16, 2), 512 threads.
// ---------------------------------------------------------------------------
__global__ __launch_bounds__(512) void retention_mfma(
    const short* __restrict__ Qb, const short* __restrict__ Kb,
    const short* __restrict__ Vt, float* __restrict__ Y,
    float* __restrict__ stats)
{
    const int x = blockIdx.x;                 // 0..15
    const int h = blockIdx.y, b = blockIdx.z;
    const int t = threadIdx.x, l = t & 63, w = t >> 6;   // w 0..7
    const int p = w >> 2, q = w & 3;
    const int lr = l & 15, g = l >> 4;

    __shared__ short S_lds[8][16 * 64];       // 16 KB, per-wave strips
    __shared__ float Yred[8][16][65];         // 33 KB, padded (+1)
    short* Sw = S_lds[w];

    const float l2g = log2f(1.0f - exp2f(-5.0f - (float)h));
    const float gstep = exp2f(l2g * 128.0f);  // gamma^128 (j descends by 128)
    // column factor gamma^{-jl} (loop-invariant)
    float cf[4];
    #pragma unroll
    for (int n = 0; n < 4; ++n) cf[n] = exp2f(-l2g * (float)(n * 16 + lr));

    const size_t kbase  = (size_t)(b * TSEQ) * DM + h * DH;
    const size_t vtbase = ((size_t)b * 1024 + h * 64) * 2048;

    float lsum = 0.f, lsq = 0.f;

    for (int phase = 0; phase < 2; ++phase) {
        const int tile = phase ? (31 - x) : x;
        const int i0 = tile * 64;

        // Q fragments: row = i0 + q*16 + lr
        const size_t qoff = (size_t)(b * TSEQ + i0 + q * 16 + lr) * DM + h * DH;
        v8s qf0 = *(const v8s*)(Qb + qoff + g * 8);
        v8s qf1 = *(const v8s*)(Qb + qoff + 32 + g * 8);

        v4f y[4];
        #pragma unroll
        for (int d = 0; d < 4; ++d) y[d] = (v4f){0.f, 0.f, 0.f, 0.f};

        // topmost j-tile of my parity
        const int jt0 = ((tile & 1) == p) ? tile : tile - 1;

        // row factor gamma^{i - j0} / 8, updated multiplicatively (j descends)
        float rowf[4];
        {
            float e0 = (float)((tile - jt0) * 64 + q * 16 + g * 4);
            #pragma unroll
            for (int r = 0; r < 4; ++r)
                rowf[r] = exp2f(l2g * (e0 + (float)r)) * 0.125f;
        }

        for (int jt = jt0; jt >= 0; jt -= 2) {
            const int j0 = jt * 64;

            // ---- S = Q K^T ----
            v4f s[4];
            #pragma unroll
            for (int n = 0; n < 4; ++n) {
                const short* kp = Kb + kbase + (size_t)(j0 + n * 16 + lr) * DM;
                v8s k0v = *(const v8s*)(kp + g * 8);
                v8s k1v = *(const v8s*)(kp + 32 + g * 8);
                v4f a = (v4f){0.f, 0.f, 0.f, 0.f};
                a = __builtin_amdgcn_mfma_f32_16x16x32_bf16(qf0, k0v, a, 0, 0, 0);
                a = __builtin_amdgcn_mfma_f32_16x16x32_bf16(qf1, k1v, a, 0, 0, 0);
                s[n] = a;
            }

            // ---- decay, bf16, swizzled per-wave LDS (no barrier) ----
            const bool diag = (jt == tile);
            #pragma unroll
            for (int n = 0; n < 4; ++n) {
                int jl = n * 16 + lr;
                #pragma unroll
                for (int r = 0; r < 4; ++r) {
                    float v = s[n][r] * rowf[r] * cf[n];
                    if (diag && (q * 16 + g * 4 + r - jl) < 0) v = 0.0f;
                    int row  = g * 4 + r;
                    int byte = (row * 128 + jl * 2) ^ ((row & 7) << 4);
                    *(short*)((char*)Sw + byte) = f2bf(v);
                }
            }

            // ---- Y += S' @ V ----
            #pragma unroll
            for (int ks = 0; ks < 2; ++ks) {
                int byte = (lr * 128 + ks * 64 + g * 16) ^ ((lr & 7) << 4);
                v8s sa = *(const v8s*)((char*)Sw + byte);
                #pragma unroll
                for (int dt = 0; dt < 4; ++dt) {
                    const short* vp = Vt + vtbase
                                    + (size_t)(dt * 16 + lr) * 2048
                                    + j0 + ks * 32 + g * 8;
                    v8s vf = *(const v8s*)vp;
                    y[dt] = __builtin_amdgcn_mfma_f32_16x16x32_bf16(
                        sa, vf, y[dt], 0, 0, 0);
                }
            }

            #pragma unroll
            for (int r = 0; r < 4; ++r) rowf[r] *= gstep;
        }

        // ---- stash parity partials, combine (1 barrier) ----
        #pragma unroll
        for (int dt = 0; dt < 4; ++dt)
            #pragma unroll
            for (int r = 0; r < 4; ++r)
                Yred[w][g * 4 + r][dt * 16 + lr] = y[dt][r];
        __syncthreads();

        if (w < 4) {
            #pragma unroll
            for (int rr = 0; rr < 16; ++rr) {
                float val = Yred[w][rr][l] + Yred[w + 4][rr][l];
                Y[(size_t)(b * TSEQ + i0 + q * 16 + rr) * DM + h * DH + l] = val;
                lsum += val; lsq += val * val;
            }
        }
        if (phase == 0) __syncthreads();   // Yred reused by phase B
    }

    // ---- GN stats (waves 0-3 hold all combined values) ----
    if (w < 4) {
        #pragma unroll
        for (int m = 32; m; m >>= 1) {
            lsum += __shfl_xor(lsum, m, 64);
            lsq  += __shfl_xor(lsq,  m, 64);
        }
        if (l == 0) {
            atomicAdd(&stats[b * NH + h],      lsum);
            atomicAdd(&stats[32 + b * NH + h], lsq);
        }
    }
}

// ---------------------------------------------------------------------------
// GroupNorm finalize: per (b, channel) scale/shift
// ---------------------------------------------------------------------------
__global__ __launch_bounds__(256) void gn_finalize(
    const float* __restrict__ stats,
    const float* __restrict__ gnw, const float* __restrict__ gnb,
    float* __restrict__ scale, float* __restrict__ shift)
{
    int idx = blockIdx.x * 256 + threadIdx.x;
    if (idx >= NB * DM) return;
    int bb = idx >> 10;
    int c  = idx & (DM - 1);
    int hh = c >> 6;
    const float n = (float)(DH * TSEQ);
    float mean = stats[bb * NH + hh] / n;
    float var  = stats[32 + bb * NH + hh] / n - mean * mean;
    float rstd = rsqrtf(var + GN_EPS);
    float sc = rstd * gnw[c];
    scale[idx] = sc;
    shift[idx] = gnb[c] - mean * sc;
}

// ---------------------------------------------------------------------------
// Apply GN -> bf16 (input to the output projection)
// ---------------------------------------------------------------------------
__global__ __launch_bounds__(256) void gn_apply(
    const float* __restrict__ Y, const float* __restrict__ scale,
    const float* __restrict__ shift, short* __restrict__ Ybf)
{
    const int total4 = (NB * TSEQ * DM) / 4;   // 1,048,576
    for (int i = blockIdx.x * 256 + threadIdx.x; i < total4;
         i += gridDim.x * 256) {
        int e = i * 4;
        int c = e & (DM - 1);
        int bb = e >> 21;
        v4f yv = *(const v4f*)(Y + e);
        v4f sc = *(const v4f*)(scale + bb * DM + c);
        v4f sh = *(const v4f*)(shift + bb * DM + c);
        v4s o;
        #pragma unroll
        for (int j = 0; j < 4; ++j) o[j] = f2bf(yv[j] * sc[j] + sh[j]);
        *(v4s*)(Ybf + e) = o;
    }
}

// ---------------------------------------------------------------------------
// Output projection: out = Ybf @ Wo^T, fp32 out.
// ---------------------------------------------------------------------------
__global__ __launch_bounds__(256) void gemm_out_mfma(
    const short* __restrict__ Ybf, const short* __restrict__ Wob,
    float* __restrict__ out)
{
    const int n0 = blockIdx.x * 128, m0 = blockIdx.y * 128;
    const int t = threadIdx.x, l = t & 63, w = t >> 6;
    const int wr = (w >> 1) * 64, wc = (w & 1) * 64;
    const int lr = l & 15, lk = (l >> 4) * 8;

    const short* Ap = Ybf + (size_t)(m0 + wr + lr) * DM + lk;
    const short* Bp = Wob + (size_t)(n0 + wc + lr) * DM + lk;

    v4f acc[4][4];
    #pragma unroll
    for (int i = 0; i < 4; ++i)
        #pragma unroll
        for (int j = 0; j < 4; ++j) acc[i][j] = (v4f){0.f, 0.f, 0.f, 0.f};

    #pragma unroll 2
    for (int k0 = 0; k0 < DM; k0 += 32) {
        v8s a[4], bb[4];
        #pragma unroll
        for (int i = 0; i < 4; ++i) {
            a[i]  = *(const v8s*)(Ap + (size_t)i * 16 * DM + k0);
            bb[i] = *(const v8s*)(Bp + (size_t)i * 16 * DM + k0);
        }
        #pragma unroll
        for (int i = 0; i < 4; ++i)
            #pragma unroll
            for (int j = 0; j < 4; ++j)
                acc[i][j] = __builtin_amdgcn_mfma_f32_16x16x32_bf16(
                    a[i], bb[j], acc[i][j], 0, 0, 0);
    }

    #pragma unroll
    for (int i = 0; i < 4; ++i) {
        int row = m0 + wr + i * 16 + (l >> 4) * 4;
        #pragma unroll
        for (int j = 0; j < 4; ++j) {
            int col = n0 + wc + j * 16 + lr;
            #pragma unroll
            for (int r = 0; r < 4; ++r)
                out[(size_t)(row + r) * DM + col] = acc[i][j][r];
        }
    }
}

// ---------------------------------------------------------------------------
extern "C" void kernel_launch(void* const* d_in, const int* in_sizes, int n_in,
                              void* d_out, int out_size, void* d_ws, size_t ws_size,
                              hipStream_t stream)
{
    const float* x   = (const float*)d_in[0];
    const float* Wq  = (const float*)d_in[1];
    const float* Wk  = (const float*)d_in[2];
    const float* Wv  = (const float*)d_in[3];
    const float* Wo  = (const float*)d_in[4];
    const float* gnw = (const float*)d_in[5];
    const float* gnb = (const float*)d_in[6];
    float* out = (float*)d_out;

    // workspace carve (bytes)
    char* wsb = (char*)d_ws;
    size_t o = 0;
    float* Y    = (float*)(wsb + o); o += (size_t)NB * TSEQ * DM * 4;
    short* Qb   = (short*)(wsb + o); o += (size_t)NB * TSEQ * DM * 2;
    short* Kb   = (short*)(wsb + o); o += (size_t)NB * TSEQ * DM * 2;
    short* Vt   = (short*)(wsb + o); o += (size_t)NB * TSEQ * DM * 2;
    short* xbf  = (short*)(wsb + o); o += (size_t)NB * TSEQ * DM * 2;
    short* wbf  = (short*)(wsb + o); o += (size_t)4 * DM * DM * 2;
    short* Ybf  = (short*)(wsb + o); o += (size_t)NB * TSEQ * DM * 2;
    float* stats = (float*)(wsb + o); o += 256;
    float* scale = (float*)(wsb + o); o += (size_t)NB * DM * 4;
    float* shift = (float*)(wsb + o); o += (size_t)NB * DM * 4;
    if (ws_size < o) return;

    cast_kernel<<<2048, 256, 0, stream>>>(x, Wq, Wk, Wv, Wo, xbf, wbf, stats);
    gemm_qkv_mfma<<<dim3(DM / 128, (NB * TSEQ) / 128, 3), 256, 0, stream>>>(
        xbf, wbf, Qb, Kb, Vt);
    retention_mfma<<<dim3(16, NH, NB), 512, 0, stream>>>(
        Qb, Kb, Vt, Y, stats);
    gn_finalize<<<dim3((NB * DM + 255) / 256), 256, 0, stream>>>(
        stats, gnw, gnb, scale, shift);
    gn_apply<<<2048, 256, 0, stream>>>(Y, scale, shift, Ybf);
    gemm_out_mfma<<<dim3(DM / 128, (NB * TSEQ) / 128), 256, 0, stream>>>(
        Ybf, wbf + 3 * (size_t)DM * DM, out);
}

// Round 4
// 236.612 us; speedup vs baseline: 5.8485x; 1.2350x over previous
//
#include <hip/hip_runtime.h>
#include <math.h>

#define TSEQ 2048
#define NB   2
#define DM   1024
#define NH   16
#define DH   64
#define GN_EPS 1e-5f

typedef short v8s __attribute__((ext_vector_type(8)));
typedef short v4s __attribute__((ext_vector_type(4)));
typedef float v4f __attribute__((ext_vector_type(4)));

__device__ __forceinline__ short f2bf(float f) {
    union { float f; unsigned u; } c; c.f = f;
    unsigned u = c.u;
    unsigned r = (u + 0x7fffu + ((u >> 16) & 1u)) >> 16;   // RNE
    return (short)r;
}

// pack two f32 -> two bf16 in one instruction (no builtin on gfx950)
__device__ __forceinline__ unsigned cvtpk_bf16(float lo, float hi) {
    unsigned r;
    asm("v_cvt_pk_bf16_f32 %0, %1, %2" : "=v"(r) : "v"(lo), "v"(hi));
    return r;
}

// ---------------------------------------------------------------------------
// cast x and the 4 weight matrices to bf16; zero the GN stats
// ---------------------------------------------------------------------------
__global__ __launch_bounds__(256) void cast_kernel(
    const float* __restrict__ x,
    const float* __restrict__ Wq, const float* __restrict__ Wk,
    const float* __restrict__ Wv, const float* __restrict__ Wo,
    short* __restrict__ xbf, short* __restrict__ wbf, float* __restrict__ stats)
{
    if (blockIdx.x == 0 && threadIdx.x < 64) stats[threadIdx.x] = 0.0f;
    const int NX = NB * TSEQ * DM;            // 4,194,304
    const int NW = DM * DM;                   // 1,048,576
    const int total4 = (NX + 4 * NW) / 4;     // 2,097,152
    for (int i = blockIdx.x * 256 + threadIdx.x; i < total4;
         i += gridDim.x * 256) {
        int e = i * 4;
        const float* src; short* dst;
        if (e < NX) { src = x + e; dst = xbf + e; }
        else {
            int o = e - NX;
            int w = o >> 20;
            int r = o & (NW - 1);
            src = (w == 0 ? Wq : w == 1 ? Wk : w == 2 ? Wv : Wo) + r;
            dst = wbf + o;
        }
        v4f v = *(const v4f*)src;
        v4s s;
        #pragma unroll
        for (int j = 0; j < 4; ++j) s[j] = f2bf(v[j]);
        *(v4s*)dst = s;
    }
}

// ---------------------------------------------------------------------------
// QKV projection, bf16 MFMA, no LDS.  Block = 128x128, 4 waves in 2x2.
// grid (8, 32, 3).  z=0: writes Q' = Q * gamma_h^(t&63) / 8  (prescaled decay)
//                   z=1: writes K' = K * gamma_h^-(t&63)
//                   z=2: writes V transposed: Vt[b][h*64+d][t]
// ---------------------------------------------------------------------------
__global__ __launch_bounds__(256) void gemm_qkv_mfma(
    const short* __restrict__ xbf, const short* __restrict__ wbf,
    short* __restrict__ Qb, short* __restrict__ Kb, short* __restrict__ Vt)
{
    const int z = blockIdx.z;
    const short* __restrict__ B = wbf + (size_t)z * (DM * DM);
    const int n0 = blockIdx.x * 128, m0 = blockIdx.y * 128;
    const int t = threadIdx.x, l = t & 63, w = t >> 6;
    const int wr = (w >> 1) * 64, wc = (w & 1) * 64;
    const int lr = l & 15, lk = (l >> 4) * 8, lg4 = (l >> 4) * 4;

    const short* Ap = xbf + (size_t)(m0 + wr + lr) * DM + lk;
    const short* Bp = B   + (size_t)(n0 + wc + lr) * DM + lk;

    v4f acc[4][4];
    #pragma unroll
    for (int i = 0; i < 4; ++i)
        #pragma unroll
        for (int j = 0; j < 4; ++j) acc[i][j] = (v4f){0.f, 0.f, 0.f, 0.f};

    #pragma unroll 2
    for (int k0 = 0; k0 < DM; k0 += 32) {
        v8s a[4], bb[4];
        #pragma unroll
        for (int i = 0; i < 4; ++i) {
            a[i]  = *(const v8s*)(Ap + (size_t)i * 16 * DM + k0);
            bb[i] = *(const v8s*)(Bp + (size_t)i * 16 * DM + k0);
        }
        #pragma unroll
        for (int i = 0; i < 4; ++i)
            #pragma unroll
            for (int j = 0; j < 4; ++j)
                acc[i][j] = __builtin_amdgcn_mfma_f32_16x16x32_bf16(
                    a[i], bb[j], acc[i][j], 0, 0, 0);
    }

    if (z < 2) {
        short* __restrict__ O = (z == 0) ? Qb : Kb;
        const float sgn = (z == 0) ? 1.0f : -1.0f;
        const float c0  = (z == 0) ? -3.0f : 0.0f;     // fold 1/8 into Q
        float l2gj[4];
        #pragma unroll
        for (int j = 0; j < 4; ++j) {
            int hh = (n0 + wc + j * 16 + lr) >> 6;
            l2gj[j] = sgn * log2f(1.0f - exp2f(-5.0f - (float)hh));
        }
        #pragma unroll
        for (int i = 0; i < 4; ++i) {
            int row = m0 + wr + i * 16 + lg4;
            #pragma unroll
            for (int j = 0; j < 4; ++j) {
                int col = n0 + wc + j * 16 + lr;
                #pragma unroll
                for (int r = 0; r < 4; ++r) {
                    int tl = (row + r) & 63;
                    float fac = exp2f(fmaf(l2gj[j], (float)tl, c0));
                    O[(size_t)(row + r) * DM + col] = f2bf(acc[i][j][r] * fac);
                }
            }
        }
    } else {
        #pragma unroll
        for (int i = 0; i < 4; ++i) {
            int row  = m0 + wr + i * 16 + lg4;
            int bidx = row >> 11, tb = row & (TSEQ - 1);
            #pragma unroll
            for (int j = 0; j < 4; ++j) {
                int col = n0 + wc + j * 16 + lr;
                v4s pk;
                #pragma unroll
                for (int r = 0; r < 4; ++r) pk[r] = f2bf(acc[i][j][r]);
                *(v4s*)(Vt + ((size_t)bidx << 21) + ((size_t)col << 11) + tb) = pk;
            }
        }
    }
}

// ---------------------------------------------------------------------------
// Retention: Y = (Q K^T * gamma^(i-j) / 8) @ V, causal.  Decay prescaled
// into Q',K'; per-j-tile residual is the uniform scalar gamma^(64*dTile).
// Swapped QK (St = K.Q^T -> lane holds consecutive j) -> cvt_pk + b64 LDS
// writes; PV computes Y^T = V^T . S with S as the B operand (b128 reads
// from the same XOR-swizzled strip).  Each wave owns 32 rows for the FULL
// causal j-range (half-tiles s and 63-s -> exactly 33 iters/wave), no
// block barriers, per-wave double-buffered strips.  Epilogue un-transposes
// Y^T through a small per-wave LDS scratch.  grid(256) 1D, XCD-chunk
// swizzled so the 8 blocks of one (b,h) share an XCD (K/Vt L2-resident).
// ---------------------------------------------------------------------------
__global__ __launch_bounds__(256) void retention_mfma(
    const short* __restrict__ Qb, const short* __restrict__ Kb,
    const short* __restrict__ Vt, float* __restrict__ Y,
    float* __restrict__ stats)
{
    const int bid = blockIdx.x;
    const int swz = (bid & 7) * 32 + (bid >> 3);     // XCD-chunked, bijective
    const int b = swz >> 7, h = (swz >> 3) & 15, xs = swz & 7;
    const int tid = threadIdx.x, l = tid & 63, w = tid >> 6;
    const int lr = l & 15, g = l >> 4;
    const int s = xs * 4 + w;                        // wave slot 0..31

    __shared__ short S_lds[4][2][2048];              // 32 KB: per-wave dbuf strips
    __shared__ float tr[4][16][68];                  // 17.4 KB: epilogue transpose

    const float l2g = log2f(1.0f - exp2f(-5.0f - (float)h));
    const float g64 = exp2f(l2g * 64.0f);            // gamma^64

    const size_t kroot = (size_t)b * TSEQ * DM + h * DH;
    const size_t vroot = ((size_t)b * DM + h * DH) * TSEQ;

    float lsum = 0.f, lsq = 0.f;

    #pragma unroll 1
    for (int phase = 0; phase < 2; ++phase) {
        const int ht = phase ? (63 - s) : s;         // half-tile (32 rows)
        const int i0 = ht * 32;
        const int jtd = ht >> 1;                     // diagonal 64-j-tile

        // Q' B-fragments (col = i = i0+ib*16+lr, k = d contiguous)
        v8s qf[2][2];
        #pragma unroll
        for (int ib = 0; ib < 2; ++ib)
            #pragma unroll
            for (int k2 = 0; k2 < 2; ++k2)
                qf[ib][k2] = *(const v8s*)(Qb + kroot
                    + (size_t)(i0 + ib * 16 + lr) * DM + k2 * 32 + g * 8);

        v4f y[4][2];
        #pragma unroll
        for (int dt = 0; dt < 4; ++dt)
            #pragma unroll
            for (int ib = 0; ib < 2; ++ib) y[dt][ib] = (v4f){0.f,0.f,0.f,0.f};

        float tf = 1.0f;                             // gamma^(64*(jtd-jt))
        for (int jt = jtd; jt >= 0; --jt) {
            const int j0 = jt * 64;
            char* Sw = (char*)&S_lds[w][jt & 1][0];

            // ---- St = K'.Q'^T : rows j, cols i ----
            v4f st[4][2];
            #pragma unroll
            for (int n = 0; n < 4; ++n) {
                const short* kp = Kb + kroot + (size_t)(j0 + n * 16 + lr) * DM;
                v8s kf0 = *(const v8s*)(kp + g * 8);
                v8s kf1 = *(const v8s*)(kp + 32 + g * 8);
                #pragma unroll
                for (int ib = 0; ib < 2; ++ib) {
                    v4f a = (v4f){0.f, 0.f, 0.f, 0.f};
                    a = __builtin_amdgcn_mfma_f32_16x16x32_bf16(kf0, qf[ib][0], a, 0, 0, 0);
                    a = __builtin_amdgcn_mfma_f32_16x16x32_bf16(kf1, qf[ib][1], a, 0, 0, 0);
                    st[n][ib] = a;
                }
            }

            // ---- uniform tile decay + diag mask + pack + swizzled b64 LDS ----
            const bool dg = (jt == jtd);
            #pragma unroll
            for (int n = 0; n < 4; ++n)
                #pragma unroll
                for (int ib = 0; ib < 2; ++ib) {
                    v4f v = st[n][ib] * tf;
                    if (dg) {
                        #pragma unroll
                        for (int r = 0; r < 4; ++r)
                            if ((i0 + ib * 16 + lr) - (j0 + n * 16 + g * 4 + r) < 0)
                                v[r] = 0.0f;
                    }
                    unsigned u0 = cvtpk_bf16(v[0], v[1]);
                    unsigned u1 = cvtpk_bf16(v[2], v[3]);
                    int byte = ((ib * 16 + lr) * 128 + n * 32 + g * 8)
                               ^ ((lr & 7) << 4);
                    *(unsigned long long*)(Sw + byte) =
                        (unsigned long long)u0 | ((unsigned long long)u1 << 32);
                }

            // ---- Y^T += V^T . S  (A = Vt rows d, B = S rows i, k = j) ----
            v8s sB[2][2];
            #pragma unroll
            for (int ib = 0; ib < 2; ++ib)
                #pragma unroll
                for (int ks = 0; ks < 2; ++ks) {
                    int byte = ((ib * 16 + lr) * 128 + ks * 64 + g * 16)
                               ^ ((lr & 7) << 4);
                    sB[ib][ks] = *(const v8s*)(Sw + byte);
                }
            #pragma unroll
            for (int dt = 0; dt < 4; ++dt)
                #pragma unroll
                for (int ks = 0; ks < 2; ++ks) {
                    v8s vf = *(const v8s*)(Vt + vroot
                        + (size_t)(dt * 16 + lr) * TSEQ + j0 + ks * 32 + g * 8);
                    #pragma unroll
                    for (int ib = 0; ib < 2; ++ib)
                        y[dt][ib] = __builtin_amdgcn_mfma_f32_16x16x32_bf16(
                            vf, sB[ib][ks], y[dt][ib], 0, 0, 0);
                }

            tf *= g64;
        }

        // ---- GN stats from regs ----
        #pragma unroll
        for (int dt = 0; dt < 4; ++dt)
            #pragma unroll
            for (int ib = 0; ib < 2; ++ib)
                #pragma unroll
                for (int r = 0; r < 4; ++r) {
                    float v = y[dt][ib][r];
                    lsum += v; lsq += v * v;
                }

        // ---- un-transpose Y^T -> Y[b][t][dm] via per-wave scratch ----
        #pragma unroll
        for (int ib = 0; ib < 2; ++ib) {
            #pragma unroll
            for (int dt = 0; dt < 4; ++dt)
                #pragma unroll
                for (int r = 0; r < 4; ++r)
                    tr[w][lr][dt * 16 + g * 4 + r] = y[dt][ib][r];
            __builtin_amdgcn_sched_barrier(0);       // keep write->read order
            #pragma unroll
            for (int u = 0; u < 4; ++u) {
                v4f val = *(const v4f*)&tr[w][lr][g * 16 + u * 4];
                *(v4f*)&Y[(size_t)(b * TSEQ + i0 + ib * 16 + lr) * DM
                          + h * DH + g * 16 + u * 4] = val;
            }
            __builtin_amdgcn_sched_barrier(0);
        }
    }

    // ---- per-wave stats -> atomics ----
    #pragma unroll
    for (int m = 32; m; m >>= 1) {
        lsum += __shfl_xor(lsum, m, 64);
        lsq  += __shfl_xor(lsq,  m, 64);
    }
    if (l == 0) {
        atomicAdd(&stats[b * NH + h],      lsum);
        atomicAdd(&stats[32 + b * NH + h], lsq);
    }
}

// ---------------------------------------------------------------------------
// GroupNorm finalize: per (b, channel) scale/shift
// ---------------------------------------------------------------------------
__global__ __launch_bounds__(256) void gn_finalize(
    const float* __restrict__ stats,
    const float* __restrict__ gnw, const float* __restrict__ gnb,
    float* __restrict__ scale, float* __restrict__ shift)
{
    int idx = blockIdx.x * 256 + threadIdx.x;
    if (idx >= NB * DM) return;
    int bb = idx >> 10;
    int c  = idx & (DM - 1);
    int hh = c >> 6;
    const float n = (float)(DH * TSEQ);
    float mean = stats[bb * NH + hh] / n;
    float var  = stats[32 + bb * NH + hh] / n - mean * mean;
    float rstd = rsqrtf(var + GN_EPS);
    float sc = rstd * gnw[c];
    scale[idx] = sc;
    shift[idx] = gnb[c] - mean * sc;
}

// ---------------------------------------------------------------------------
// Apply GN -> bf16 (input to the output projection)
// ---------------------------------------------------------------------------
__global__ __launch_bounds__(256) void gn_apply(
    const float* __restrict__ Y, const float* __restrict__ scale,
    const float* __restrict__ shift, short* __restrict__ Ybf)
{
    const int total4 = (NB * TSEQ * DM) / 4;   // 1,048,576
    for (int i = blockIdx.x * 256 + threadIdx.x; i < total4;
         i += gridDim.x * 256) {
        int e = i * 4;
        int c = e & (DM - 1);
        int bb = e >> 21;
        v4f yv = *(const v4f*)(Y + e);
        v4f sc = *(const v4f*)(scale + bb * DM + c);
        v4f sh = *(const v4f*)(shift + bb * DM + c);
        v4s o;
        #pragma unroll
        for (int j = 0; j < 4; ++j) o[j] = f2bf(yv[j] * sc[j] + sh[j]);
        *(v4s*)(Ybf + e) = o;
    }
}

// ---------------------------------------------------------------------------
// Output projection: out = Ybf @ Wo^T, fp32 out.
// ---------------------------------------------------------------------------
__global__ __launch_bounds__(256) void gemm_out_mfma(
    const short* __restrict__ Ybf, const short* __restrict__ Wob,
    float* __restrict__ out)
{
    const int n0 = blockIdx.x * 128, m0 = blockIdx.y * 128;
    const int t = threadIdx.x, l = t & 63, w = t >> 6;
    const int wr = (w >> 1) * 64, wc = (w & 1) * 64;
    const int lr = l & 15, lk = (l >> 4) * 8;

    const short* Ap = Ybf + (size_t)(m0 + wr + lr) * DM + lk;
    const short* Bp = Wob + (size_t)(n0 + wc + lr) * DM + lk;

    v4f acc[4][4];
    #pragma unroll
    for (int i = 0; i < 4; ++i)
        #pragma unroll
        for (int j = 0; j < 4; ++j) acc[i][j] = (v4f){0.f, 0.f, 0.f, 0.f};

    #pragma unroll 2
    for (int k0 = 0; k0 < DM; k0 += 32) {
        v8s a[4], bb[4];
        #pragma unroll
        for (int i = 0; i < 4; ++i) {
            a[i]  = *(const v8s*)(Ap + (size_t)i * 16 * DM + k0);
            bb[i] = *(const v8s*)(Bp + (size_t)i * 16 * DM + k0);
        }
        #pragma unroll
        for (int i = 0; i < 4; ++i)
            #pragma unroll
            for (int j = 0; j < 4; ++j)
                acc[i][j] = __builtin_amdgcn_mfma_f32_16x16x32_bf16(
                    a[i], bb[j], acc[i][j], 0, 0, 0);
    }

    #pragma unroll
    for (int i = 0; i < 4; ++i) {
        int row = m0 + wr + i * 16 + (l >> 4) * 4;
        #pragma unroll
        for (int j = 0; j < 4; ++j) {
            int col = n0 + wc + j * 16 + lr;
            #pragma unroll
            for (int r = 0; r < 4; ++r)
                out[(size_t)(row + r) * DM + col] = acc[i][j][r];
        }
    }
}

// ---------------------------------------------------------------------------
extern "C" void kernel_launch(void* const* d_in, const int* in_sizes, int n_in,
                              void* d_out, int out_size, void* d_ws, size_t ws_size,
                              hipStream_t stream)
{
    const float* x   = (const float*)d_in[0];
    const float* Wq  = (const float*)d_in[1];
    const float* Wk  = (const float*)d_in[2];
    const float* Wv  = (const float*)d_in[3];
    const float* Wo  = (const float*)d_in[4];
    const float* gnw = (const float*)d_in[5];
    const float* gnb = (const float*)d_in[6];
    float* out = (float*)d_out;

    // workspace carve (bytes)
    char* wsb = (char*)d_ws;
    size_t o = 0;
    float* Y    = (float*)(wsb + o); o += (size_t)NB * TSEQ * DM * 4;
    short* Qb   = (short*)(wsb + o); o += (size_t)NB * TSEQ * DM * 2;
    short* Kb   = (short*)(wsb + o); o += (size_t)NB * TSEQ * DM * 2;
    short* Vt   = (short*)(wsb + o); o += (size_t)NB * TSEQ * DM * 2;
    short* xbf  = (short*)(wsb + o); o += (size_t)NB * TSEQ * DM * 2;
    short* wbf  = (short*)(wsb + o); o += (size_t)4 * DM * DM * 2;
    short* Ybf  = (short*)(wsb + o); o += (size_t)NB * TSEQ * DM * 2;
    float* stats = (float*)(wsb + o); o += 256;
    float* scale = (float*)(wsb + o); o += (size_t)NB * DM * 4;
    float* shift = (float*)(wsb + o); o += (size_t)NB * DM * 4;
    if (ws_size < o) return;

    cast_kernel<<<2048, 256, 0, stream>>>(x, Wq, Wk, Wv, Wo, xbf, wbf, stats);
    gemm_qkv_mfma<<<dim3(DM / 128, (NB * TSEQ) / 128, 3), 256, 0, stream>>>(
        xbf, wbf, Qb, Kb, Vt);
    retention_mfma<<<dim3(256), 256, 0, stream>>>(
        Qb, Kb, Vt, Y, stats);
    gn_finalize<<<dim3((NB * DM + 255) / 256), 256, 0, stream>>>(
        stats, gnw, gnb, scale, shift);
    gn_apply<<<2048, 256, 0, stream>>>(Y, scale, shift, Ybf);
    gemm_out_mfma<<<dim3(DM / 128, (NB * TSEQ) / 128), 256, 0, stream>>>(
        Ybf, wbf + 3 * (size_t)DM * DM, out);
}

// Round 5
// 150.174 us; speedup vs baseline: 9.2149x; 1.5756x over previous
//
#include <hip/hip_runtime.h>
#include <math.h>

#define TSEQ 2048
#define NB   2
#define DM   1024
#define NH   16
#define DH   64
#define GN_EPS 1e-5f

typedef short v8s __attribute__((ext_vector_type(8)));
typedef short v4s __attribute__((ext_vector_type(4)));
typedef float v4f __attribute__((ext_vector_type(4)));

__device__ __forceinline__ short f2bf(float f) {
    union { float f; unsigned u; } c; c.f = f;
    unsigned u = c.u;
    unsigned r = (u + 0x7fffu + ((u >> 16) & 1u)) >> 16;   // RNE
    return (short)r;
}

// pack two f32 -> two bf16 in one instruction (no builtin on gfx950)
__device__ __forceinline__ unsigned cvtpk_bf16(float lo, float hi) {
    unsigned r;
    asm("v_cvt_pk_bf16_f32 %0, %1, %2" : "=v"(r) : "v"(lo), "v"(hi));
    return r;
}

// async global->LDS, 16B per lane.  LDS dest = wave-uniform base + lane*16.
__device__ __forceinline__ void gl_lds16(const void* g, void* l) {
    __builtin_amdgcn_global_load_lds(
        (const __attribute__((address_space(1))) void*)g,
        (__attribute__((address_space(3))) void*)l, 16, 0, 0);
}

// ---------------------------------------------------------------------------
// cast x and the 4 weight matrices to bf16; zero the GN stats
// ---------------------------------------------------------------------------
__global__ __launch_bounds__(256) void cast_kernel(
    const float* __restrict__ x,
    const float* __restrict__ Wq, const float* __restrict__ Wk,
    const float* __restrict__ Wv, const float* __restrict__ Wo,
    short* __restrict__ xbf, short* __restrict__ wbf, float* __restrict__ stats)
{
    if (blockIdx.x == 0 && threadIdx.x < 64) stats[threadIdx.x] = 0.0f;
    const int NX = NB * TSEQ * DM;            // 4,194,304
    const int NW = DM * DM;                   // 1,048,576
    const int total4 = (NX + 4 * NW) / 4;     // 2,097,152
    for (int i = blockIdx.x * 256 + threadIdx.x; i < total4;
         i += gridDim.x * 256) {
        int e = i * 4;
        const float* src; short* dst;
        if (e < NX) { src = x + e; dst = xbf + e; }
        else {
            int o = e - NX;
            int w = o >> 20;
            int r = o & (NW - 1);
            src = (w == 0 ? Wq : w == 1 ? Wk : w == 2 ? Wv : Wo) + r;
            dst = wbf + o;
        }
        v4f v = *(const v4f*)src;
        v4s s;
        #pragma unroll
        for (int j = 0; j < 4; ++j) s[j] = f2bf(v[j]);
        *(v4s*)dst = s;
    }
}

// ---------------------------------------------------------------------------
// QKV projection, bf16 MFMA, m97-style: 128x128 tile, BK=64, single 32KB
// LDS buffer staged via global_load_lds(16B) with linear dest + pre-swizzled
// source; ds_read_b128 with the same XOR swizzle (conflict-free).
// grid (8, 32, 3).  z=0: Q' = Q * gamma_h^(t&63) / 8;  z=1: K' * gamma^-(t&63)
//                   z=2: V transposed -> Vt[b][h*64+d][t]
// ---------------------------------------------------------------------------
__global__ __launch_bounds__(256, 3) void gemm_qkv_mfma(
    const short* __restrict__ xbf, const short* __restrict__ wbf,
    short* __restrict__ Qb, short* __restrict__ Kb, short* __restrict__ Vt)
{
    const int z = blockIdx.z;
    const short* __restrict__ Bmat = wbf + (size_t)z * (DM * DM);
    const int n0 = blockIdx.x * 128, m0 = blockIdx.y * 128;
    const int t = threadIdx.x, l = t & 63, w = t >> 6;
    const int wr = (w >> 1) * 64, wc = (w & 1) * 64;
    const int lr = l & 15, g = l >> 4, lg4 = g * 4;

    __shared__ short As[128 * 64];
    __shared__ short Bs[128 * 64];

    v4f acc[4][4];
    #pragma unroll
    for (int i = 0; i < 4; ++i)
        #pragma unroll
        for (int j = 0; j < 4; ++j) acc[i][j] = (v4f){0.f, 0.f, 0.f, 0.f};

    const char* Agp = (const char*)(xbf  + (size_t)m0 * DM);
    const char* Bgp = (const char*)(Bmat + (size_t)n0 * DM);

    // staging constants: chunk i = p*256+t; dest linear, source pre-swizzled
    int soff[4], sdst[4];
    #pragma unroll
    for (int p = 0; p < 4; ++p) {
        int i = p * 256 + t;
        int row = i >> 3;
        int cp  = (i & 7) * 16;
        soff[p] = row * (DM * 2) + (cp ^ ((row & 7) << 4));
        sdst[p] = (p * 256 + (t & 192)) * 16;      // wave-uniform base
    }
    const int swz = (lr & 7) << 4;

    for (int kt = 0; kt < DM / 64; ++kt) {
        const int kb = kt * 128;                    // k0 byte offset in row
        #pragma unroll
        for (int p = 0; p < 4; ++p) {
            gl_lds16(Agp + (size_t)soff[p] + kb, (char*)As + sdst[p]);
            gl_lds16(Bgp + (size_t)soff[p] + kb, (char*)Bs + sdst[p]);
        }
        asm volatile("s_waitcnt vmcnt(0)" ::: "memory");
        __syncthreads();

        v8s bfr[4][2];
        #pragma unroll
        for (int j = 0; j < 4; ++j) {
            int rowb = wc + j * 16 + lr;
            #pragma unroll
            for (int ks = 0; ks < 2; ++ks)
                bfr[j][ks] = *(const v8s*)((const char*)Bs + rowb * 128
                               + ((ks * 64 + g * 16) ^ swz));
        }
        #pragma unroll
        for (int i = 0; i < 4; ++i) {
            int rowa = wr + i * 16 + lr;
            v8s a0 = *(const v8s*)((const char*)As + rowa * 128 + ((g * 16) ^ swz));
            v8s a1 = *(const v8s*)((const char*)As + rowa * 128 + ((64 + g * 16) ^ swz));
            #pragma unroll
            for (int j = 0; j < 4; ++j) {
                acc[i][j] = __builtin_amdgcn_mfma_f32_16x16x32_bf16(
                    a0, bfr[j][0], acc[i][j], 0, 0, 0);
                acc[i][j] = __builtin_amdgcn_mfma_f32_16x16x32_bf16(
                    a1, bfr[j][1], acc[i][j], 0, 0, 0);
            }
        }
        __syncthreads();
    }

    if (z < 2) {
        short* __restrict__ O = (z == 0) ? Qb : Kb;
        const float sgn = (z == 0) ? 1.0f : -1.0f;
        const float c0  = (z == 0) ? -3.0f : 0.0f;     // fold 1/8 into Q
        float l2gj[4];
        #pragma unroll
        for (int j = 0; j < 4; ++j) {
            int hh = (n0 + wc + j * 16 + lr) >> 6;
            l2gj[j] = sgn * log2f(1.0f - exp2f(-5.0f - (float)hh));
        }
        #pragma unroll
        for (int i = 0; i < 4; ++i) {
            int row = m0 + wr + i * 16 + lg4;
            #pragma unroll
            for (int j = 0; j < 4; ++j) {
                int col = n0 + wc + j * 16 + lr;
                #pragma unroll
                for (int r = 0; r < 4; ++r) {
                    int tl = (row + r) & 63;
                    float fac = exp2f(fmaf(l2gj[j], (float)tl, c0));
                    O[(size_t)(row + r) * DM + col] = f2bf(acc[i][j][r] * fac);
                }
            }
        }
    } else {
        #pragma unroll
        for (int i = 0; i < 4; ++i) {
            int row  = m0 + wr + i * 16 + lg4;
            int bidx = row >> 11, tb = row & (TSEQ - 1);
            #pragma unroll
            for (int j = 0; j < 4; ++j) {
                int col = n0 + wc + j * 16 + lr;
                v4s pk;
                #pragma unroll
                for (int r = 0; r < 4; ++r) pk[r] = f2bf(acc[i][j][r]);
                *(v4s*)(Vt + ((size_t)bidx << 21) + ((size_t)col << 11) + tb) = pk;
            }
        }
    }
}

// ---------------------------------------------------------------------------
// Retention: Y = (Q K^T * gamma^(i-j) / 8) @ V, causal.  Decay prescaled
// into Q',K'; per-j-tile residual is the uniform scalar gamma^(64*dTile).
// Swapped QK (St = K.Q^T), cvt_pk + b64 swizzled LDS, PV as Y^T = V^T.S.
// Each wave owns 32 rows, full causal j-range (pair s and 63-s -> 33
// iters/wave), no block barriers.  grid(256), XCD-chunk swizzled.
// ---------------------------------------------------------------------------
__global__ __launch_bounds__(256) void retention_mfma(
    const short* __restrict__ Qb, const short* __restrict__ Kb,
    const short* __restrict__ Vt, float* __restrict__ Y,
    float* __restrict__ stats)
{
    const int bid = blockIdx.x;
    const int swz = (bid & 7) * 32 + (bid >> 3);     // XCD-chunked, bijective
    const int b = swz >> 7, h = (swz >> 3) & 15, xs = swz & 7;
    const int tid = threadIdx.x, l = tid & 63, w = tid >> 6;
    const int lr = l & 15, g = l >> 4;
    const int s = xs * 4 + w;                        // wave slot 0..31

    __shared__ short S_lds[4][2][2048];              // 32 KB per-wave dbuf
    __shared__ float tr[4][16][68];                  // epilogue transpose

    const float l2g = log2f(1.0f - exp2f(-5.0f - (float)h));
    const float g64 = exp2f(l2g * 64.0f);            // gamma^64

    const size_t kroot = (size_t)b * TSEQ * DM + h * DH;
    const size_t vroot = ((size_t)b * DM + h * DH) * TSEQ;

    float lsum = 0.f, lsq = 0.f;

    #pragma unroll 1
    for (int phase = 0; phase < 2; ++phase) {
        const int ht = phase ? (63 - s) : s;         // half-tile (32 rows)
        const int i0 = ht * 32;
        const int jtd = ht >> 1;                     // diagonal 64-j-tile

        v8s qf[2][2];
        #pragma unroll
        for (int ib = 0; ib < 2; ++ib)
            #pragma unroll
            for (int k2 = 0; k2 < 2; ++k2)
                qf[ib][k2] = *(const v8s*)(Qb + kroot
                    + (size_t)(i0 + ib * 16 + lr) * DM + k2 * 32 + g * 8);

        v4f y[4][2];
        #pragma unroll
        for (int dt = 0; dt < 4; ++dt)
            #pragma unroll
            for (int ib = 0; ib < 2; ++ib) y[dt][ib] = (v4f){0.f,0.f,0.f,0.f};

        float tf = 1.0f;                             // gamma^(64*(jtd-jt))
        for (int jt = jtd; jt >= 0; --jt) {
            const int j0 = jt * 64;
            char* Sw = (char*)&S_lds[w][jt & 1][0];

            v4f st[4][2];
            #pragma unroll
            for (int n = 0; n < 4; ++n) {
                const short* kp = Kb + kroot + (size_t)(j0 + n * 16 + lr) * DM;
                v8s kf0 = *(const v8s*)(kp + g * 8);
                v8s kf1 = *(const v8s*)(kp + 32 + g * 8);
                #pragma unroll
                for (int ib = 0; ib < 2; ++ib) {
                    v4f a = (v4f){0.f, 0.f, 0.f, 0.f};
                    a = __builtin_amdgcn_mfma_f32_16x16x32_bf16(kf0, qf[ib][0], a, 0, 0, 0);
                    a = __builtin_amdgcn_mfma_f32_16x16x32_bf16(kf1, qf[ib][1], a, 0, 0, 0);
                    st[n][ib] = a;
                }
            }

            const bool dg = (jt == jtd);
            #pragma unroll
            for (int n = 0; n < 4; ++n)
                #pragma unroll
                for (int ib = 0; ib < 2; ++ib) {
                    v4f v = st[n][ib] * tf;
                    if (dg) {
                        #pragma unroll
                        for (int r = 0; r < 4; ++r)
                            if ((i0 + ib * 16 + lr) - (j0 + n * 16 + g * 4 + r) < 0)
                                v[r] = 0.0f;
                    }
                    unsigned u0 = cvtpk_bf16(v[0], v[1]);
                    unsigned u1 = cvtpk_bf16(v[2], v[3]);
                    int byte = ((ib * 16 + lr) * 128 + n * 32 + g * 8)
                               ^ ((lr & 7) << 4);
                    *(unsigned long long*)(Sw + byte) =
                        (unsigned long long)u0 | ((unsigned long long)u1 << 32);
                }

            v8s sB[2][2];
            #pragma unroll
            for (int ib = 0; ib < 2; ++ib)
                #pragma unroll
                for (int ks = 0; ks < 2; ++ks) {
                    int byte = ((ib * 16 + lr) * 128 + ks * 64 + g * 16)
                               ^ ((lr & 7) << 4);
                    sB[ib][ks] = *(const v8s*)(Sw + byte);
                }
            #pragma unroll
            for (int dt = 0; dt < 4; ++dt)
                #pragma unroll
                for (int ks = 0; ks < 2; ++ks) {
                    v8s vf = *(const v8s*)(Vt + vroot
                        + (size_t)(dt * 16 + lr) * TSEQ + j0 + ks * 32 + g * 8);
                    #pragma unroll
                    for (int ib = 0; ib < 2; ++ib)
                        y[dt][ib] = __builtin_amdgcn_mfma_f32_16x16x32_bf16(
                            vf, sB[ib][ks], y[dt][ib], 0, 0, 0);
                }

            tf *= g64;
        }

        #pragma unroll
        for (int dt = 0; dt < 4; ++dt)
            #pragma unroll
            for (int ib = 0; ib < 2; ++ib)
                #pragma unroll
                for (int r = 0; r < 4; ++r) {
                    float v = y[dt][ib][r];
                    lsum += v; lsq += v * v;
                }

        #pragma unroll
        for (int ib = 0; ib < 2; ++ib) {
            #pragma unroll
            for (int dt = 0; dt < 4; ++dt)
                #pragma unroll
                for (int r = 0; r < 4; ++r)
                    tr[w][lr][dt * 16 + g * 4 + r] = y[dt][ib][r];
            __builtin_amdgcn_sched_barrier(0);
            #pragma unroll
            for (int u = 0; u < 4; ++u) {
                v4f val = *(const v4f*)&tr[w][lr][g * 16 + u * 4];
                *(v4f*)&Y[(size_t)(b * TSEQ + i0 + ib * 16 + lr) * DM
                          + h * DH + g * 16 + u * 4] = val;
            }
            __builtin_amdgcn_sched_barrier(0);
        }
    }

    #pragma unroll
    for (int m = 32; m; m >>= 1) {
        lsum += __shfl_xor(lsum, m, 64);
        lsq  += __shfl_xor(lsq,  m, 64);
    }
    if (l == 0) {
        atomicAdd(&stats[b * NH + h],      lsum);
        atomicAdd(&stats[32 + b * NH + h], lsq);
    }
}

// ---------------------------------------------------------------------------
// GroupNorm finalize: per (b, channel) scale/shift
// ---------------------------------------------------------------------------
__global__ __launch_bounds__(256) void gn_finalize(
    const float* __restrict__ stats,
    const float* __restrict__ gnw, const float* __restrict__ gnb,
    float* __restrict__ scale, float* __restrict__ shift)
{
    int idx = blockIdx.x * 256 + threadIdx.x;
    if (idx >= NB * DM) return;
    int bb = idx >> 10;
    int c  = idx & (DM - 1);
    int hh = c >> 6;
    const float n = (float)(DH * TSEQ);
    float mean = stats[bb * NH + hh] / n;
    float var  = stats[32 + bb * NH + hh] / n - mean * mean;
    float rstd = rsqrtf(var + GN_EPS);
    float sc = rstd * gnw[c];
    scale[idx] = sc;
    shift[idx] = gnb[c] - mean * sc;
}

// ---------------------------------------------------------------------------
// Apply GN -> bf16 (input to the output projection)
// ---------------------------------------------------------------------------
__global__ __launch_bounds__(256) void gn_apply(
    const float* __restrict__ Y, const float* __restrict__ scale,
    const float* __restrict__ shift, short* __restrict__ Ybf)
{
    const int total4 = (NB * TSEQ * DM) / 4;   // 1,048,576
    for (int i = blockIdx.x * 256 + threadIdx.x; i < total4;
         i += gridDim.x * 256) {
        int e = i * 4;
        int c = e & (DM - 1);
        int bb = e >> 21;
        v4f yv = *(const v4f*)(Y + e);
        v4f sc = *(const v4f*)(scale + bb * DM + c);
        v4f sh = *(const v4f*)(shift + bb * DM + c);
        v4s o;
        #pragma unroll
        for (int j = 0; j < 4; ++j) o[j] = f2bf(yv[j] * sc[j] + sh[j]);
        *(v4s*)(Ybf + e) = o;
    }
}

// ---------------------------------------------------------------------------
// Output projection: out = Ybf @ Wo^T, fp32 out.  Same m97-style main loop.
// ---------------------------------------------------------------------------
__global__ __launch_bounds__(256, 3) void gemm_out_mfma(
    const short* __restrict__ Ybf, const short* __restrict__ Wob,
    float* __restrict__ out)
{
    const int n0 = blockIdx.x * 128, m0 = blockIdx.y * 128;
    const int t = threadIdx.x, l = t & 63, w = t >> 6;
    const int wr = (w >> 1) * 64, wc = (w & 1) * 64;
    const int lr = l & 15, g = l >> 4;

    __shared__ short As[128 * 64];
    __shared__ short Bs[128 * 64];

    v4f acc[4][4];
    #pragma unroll
    for (int i = 0; i < 4; ++i)
        #pragma unroll
        for (int j = 0; j < 4; ++j) acc[i][j] = (v4f){0.f, 0.f, 0.f, 0.f};

    const char* Agp = (const char*)(Ybf + (size_t)m0 * DM);
    const char* Bgp = (const char*)(Wob + (size_t)n0 * DM);

    int soff[4], sdst[4];
    #pragma unroll
    for (int p = 0; p < 4; ++p) {
        int i = p * 256 + t;
        int row = i >> 3;
        int cp  = (i & 7) * 16;
        soff[p] = row * (DM * 2) + (cp ^ ((row & 7) << 4));
        sdst[p] = (p * 256 + (t & 192)) * 16;
    }
    const int swz = (lr & 7) << 4;

    for (int kt = 0; kt < DM / 64; ++kt) {
        const int kb = kt * 128;
        #pragma unroll
        for (int p = 0; p < 4; ++p) {
            gl_lds16(Agp + (size_t)soff[p] + kb, (char*)As + sdst[p]);
            gl_lds16(Bgp + (size_t)soff[p] + kb, (char*)Bs + sdst[p]);
        }
        asm volatile("s_waitcnt vmcnt(0)" ::: "memory");
        __syncthreads();

        v8s bfr[4][2];
        #pragma unroll
        for (int j = 0; j < 4; ++j) {
            int rowb = wc + j * 16 + lr;
            #pragma unroll
            for (int ks = 0; ks < 2; ++ks)
                bfr[j][ks] = *(const v8s*)((const char*)Bs + rowb * 128
                               + ((ks * 64 + g * 16) ^ swz));
        }
        #pragma unroll
        for (int i = 0; i < 4; ++i) {
            int rowa = wr + i * 16 + lr;
            v8s a0 = *(const v8s*)((const char*)As + rowa * 128 + ((g * 16) ^ swz));
            v8s a1 = *(const v8s*)((const char*)As + rowa * 128 + ((64 + g * 16) ^ swz));
            #pragma unroll
            for (int j = 0; j < 4; ++j) {
                acc[i][j] = __builtin_amdgcn_mfma_f32_16x16x32_bf16(
                    a0, bfr[j][0], acc[i][j], 0, 0, 0);
                acc[i][j] = __builtin_amdgcn_mfma_f32_16x16x32_bf16(
                    a1, bfr[j][1], acc[i][j], 0, 0, 0);
            }
        }
        __syncthreads();
    }

    #pragma unroll
    for (int i = 0; i < 4; ++i) {
        int row = m0 + wr + i * 16 + g * 4;
        #pragma unroll
        for (int j = 0; j < 4; ++j) {
            int col = n0 + wc + j * 16 + lr;
            #pragma unroll
            for (int r = 0; r < 4; ++r)
                out[(size_t)(row + r) * DM + col] = acc[i][j][r];
        }
    }
}

// ---------------------------------------------------------------------------
extern "C" void kernel_launch(void* const* d_in, const int* in_sizes, int n_in,
                              void* d_out, int out_size, void* d_ws, size_t ws_size,
                              hipStream_t stream)
{
    const float* x   = (const float*)d_in[0];
    const float* Wq  = (const float*)d_in[1];
    const float* Wk  = (const float*)d_in[2];
    const float* Wv  = (const float*)d_in[3];
    const float* Wo  = (const float*)d_in[4];
    const float* gnw = (const float*)d_in[5];
    const float* gnb = (const float*)d_in[6];
    float* out = (float*)d_out;

    // workspace carve (bytes)
    char* wsb = (char*)d_ws;
    size_t o = 0;
    float* Y    = (float*)(wsb + o); o += (size_t)NB * TSEQ * DM * 4;
    short* Qb   = (short*)(wsb + o); o += (size_t)NB * TSEQ * DM * 2;
    short* Kb   = (short*)(wsb + o); o += (size_t)NB * TSEQ * DM * 2;
    short* Vt   = (short*)(wsb + o); o += (size_t)NB * TSEQ * DM * 2;
    short* xbf  = (short*)(wsb + o); o += (size_t)NB * TSEQ * DM * 2;
    short* wbf  = (short*)(wsb + o); o += (size_t)4 * DM * DM * 2;
    short* Ybf  = (short*)(wsb + o); o += (size_t)NB * TSEQ * DM * 2;
    float* stats = (float*)(wsb + o); o += 256;
    float* scale = (float*)(wsb + o); o += (size_t)NB * DM * 4;
    float* shift = (float*)(wsb + o); o += (size_t)NB * DM * 4;
    if (ws_size < o) return;

    cast_kernel<<<2048, 256, 0, stream>>>(x, Wq, Wk, Wv, Wo, xbf, wbf, stats);
    gemm_qkv_mfma<<<dim3(DM / 128, (NB * TSEQ) / 128, 3), 256, 0, stream>>>(
        xbf, wbf, Qb, Kb, Vt);
    retention_mfma<<<dim3(256), 256, 0, stream>>>(
        Qb, Kb, Vt, Y, stats);
    gn_finalize<<<dim3((NB * DM + 255) / 256), 256, 0, stream>>>(
        stats, gnw, gnb, scale, shift);
    gn_apply<<<2048, 256, 0, stream>>>(Y, scale, shift, Ybf);
    gemm_out_mfma<<<dim3(DM / 128, (NB * TSEQ) / 128), 256, 0, stream>>>(
        Ybf, wbf + 3 * (size_t)DM * DM, out);
}